// Round 16
// baseline (569.692 us; speedup 1.0000x reference)
//
#include <hip/hip_runtime.h>
#include <stdint.h>

#define NA 200000
#define NB 200000
#define NG 10000

typedef short bf16x8 __attribute__((ext_vector_type(8)));
typedef float f32x4 __attribute__((ext_vector_type(4)));

__device__ __forceinline__ float bf2f(unsigned short u){
  union { unsigned int i; float f; } v; v.i = ((unsigned int)u) << 16; return v.f;
}
__device__ __forceinline__ unsigned short f2bf(float f){
  union { float f; unsigned int i; } v; v.f = f;
  unsigned int x = v.i;
  unsigned int r = (x + 0x7FFFu + ((x >> 16) & 1u)) >> 16;
  if ((x & 0x7F800000u) == 0x7F800000u) r = x >> 16;
  return (unsigned short)r;
}
__device__ __forceinline__ unsigned int cvtpk(float lo, float hi){
  unsigned int r;
  asm("v_cvt_pk_bf16_f32 %0, %1, %2" : "=v"(r) : "v"(lo), "v"(hi));
  return r;
}
__device__ __forceinline__ void atomic_pk_add(unsigned int* addr, unsigned int pk){
  asm volatile("global_atomic_pk_add_bf16 %0, %1, off" :: "v"(addr), "v"(pk) : "memory");
}
__device__ __forceinline__ unsigned int scale_pk(unsigned int pk, float inv){
  union { unsigned int u; float f; } lo, hi;
  lo.u = pk << 16; hi.u = pk & 0xffff0000u;
  return cvtpk(lo.f * inv, hi.f * inv);
}
__device__ __forceinline__ float softplus_f(float x){
  float t = __builtin_exp2f(-fabsf(x) * 1.44269504089f);
  return fmaxf(x, 0.0f) + 0.69314718056f * __builtin_log2f(1.0f + t);
}
__device__ __forceinline__ float ldv(const void* p, size_t off, int isbf){
  return isbf ? bf2f(((const unsigned short*)p)[off]) : ((const float*)p)[off];
}
__device__ __forceinline__ int clampi(int v, int hi){
  return v < 0 ? 0 : (v > hi ? hi : v);
}
__device__ __forceinline__ uint4 load8bf(const void* p, size_t off, int isbf){
  if (isbf) return *(const uint4*)((const unsigned short*)p + off);
  const float4* f4 = (const float4*)((const float*)p + off);
  float4 a = f4[0], b = f4[1];
  uint4 r;
  r.x = cvtpk(a.x, a.y); r.y = cvtpk(a.z, a.w);
  r.z = cvtpk(b.x, b.y); r.w = cvtpk(b.z, b.w);
  return r;
}
__device__ __forceinline__ uint4 mean8(const float* sp, float cv){
  float inv = cv > 0.f ? 1.f / cv : 0.f;
  const float4* s4 = (const float4*)sp;
  float4 a = s4[0], b = s4[1];
  uint4 r;
  r.x = cvtpk(a.x * inv, a.y * inv); r.y = cvtpk(a.z * inv, a.w * inv);
  r.z = cvtpk(b.x * inv, b.y * inv); r.w = cvtpk(b.z * inv, b.w * inv);
  return r;
}
__device__ __forceinline__ uint4 mean8pk(const void* s, size_t dw, float cv){
  float inv = cv > 0.f ? 1.f / cv : 0.f;
  uint4 p = *(const uint4*)((const unsigned int*)s + dw);
  uint4 r;
  r.x = scale_pk(p.x, inv); r.y = scale_pk(p.y, inv);
  r.z = scale_pk(p.z, inv); r.w = scale_pk(p.w, inv);
  return r;
}

__global__ void sentinel(float* outf, float code){ outf[0] = code; }

// ---- merged setup: probe (block 0) + all weight repacks (512 frag-blocks) ----
struct SetupP { const void* w[9]; };
__global__ __launch_bounds__(64) void setup_all(
    SetupP p, unsigned short* __restrict__ wp,
    const unsigned short* __restrict__ af, const int* __restrict__ amol,
    int* __restrict__ fl)
{
  const int l = threadIdx.x;
  const unsigned short* w0 = (const unsigned short*)p.w[0];
  unsigned short uw = w0[2 * l];
  int ew = (uw >> 7) & 0xFF;
  unsigned long long mw = __ballot(ew >= 0x70 && ew <= 0x8F);
  int wbf = (__popcll(mw) >= 32) ? 1 : 0;
  if (blockIdx.x == 0) {
    unsigned short ua = af[2 * l];
    int ea = (ua >> 7) & 0xFF;
    unsigned long long ma = __ballot(ea >= 0x70 && ea <= 0x8F);
    unsigned long long mi = __ballot(amol[2 * l + 1] == 0);
    if (l == 0) {
      fl[0] = (__popcll(ma) >= 32) ? 1 : 0;
      fl[1] = wbf;
      fl[2] = (__popcll(mi) == 64) ? 1 : 0;
    }
  }
  const int off[10] = {0, 96, 128, 160, 288, 320, 352, 448, 480, 512};
  int b = blockIdx.x;
  int m = 0;
  #pragma unroll
  for (int i = 0; i < 9; i++) if (b >= off[i + 1]) m = i + 1;
  int f = b - off[m];
  const void* w = p.w[m];
  int kt = f >> 3, nb = f & 7;
  alignas(16) unsigned short t[8];
  #pragma unroll
  for (int i = 0; i < 8; i++) {
    size_t o = (size_t)(kt * 32 + ((l >> 4) << 3) + i) * 128 + nb * 16 + (l & 15);
    t[i] = f2bf(ldv(w, o, wbf));
  }
  *(uint4*)(wp + (size_t)b * 512 + l * 8) = *(const uint4*)t;
}

// ---- feature bf16 prepass: atomF -> aBf (opt), globF -> gBf (opt) ----
__global__ __launch_bounds__(256) void cvt_feats(
    const void* __restrict__ af, const void* __restrict__ gf,
    unsigned int* __restrict__ aBf, unsigned int* __restrict__ gBf,
    const int* __restrict__ fl)
{
  const int featbf = fl[0];
  size_t na64 = (size_t)NA * 64;
  size_t tot = (aBf ? na64 : 0) + (gBf ? (size_t)NG * 64 : 0);
  size_t stride = (size_t)gridDim.x * 256;
  for (size_t i = (size_t)blockIdx.x * 256 + threadIdx.x; i < tot; i += stride) {
    bool isA = aBf && i < na64;
    const void* src = isA ? af : gf;
    size_t o = isA ? i : i - (aBf ? na64 : 0);
    unsigned int pk;
    if (featbf) pk = ((const unsigned int*)src)[o];
    else { float2 f = ((const float2*)src)[o]; pk = cvtpk(f.x, f.y); }
    (isA ? aBf : gBf)[o] = pk;
  }
}

// ---- bond->atom edge sum: packed bf16 atomics + free bondBf copy ----
__global__ __launch_bounds__(256) void edge_sum_pk(
    const void* __restrict__ bond, const int* __restrict__ ba,
    unsigned int* __restrict__ sums, float* __restrict__ cnt,
    unsigned int* __restrict__ bondBf, const int* __restrict__ fl)
{
  const int featbf = fl[0];
  const int istr = 1 + fl[2];
  int cp = threadIdx.x & 63;
  int rl = threadIdx.x >> 6;
  for (long b = (long)blockIdx.x * 4 + rl; b < NB; b += (long)gridDim.x * 4) {
    unsigned int pk;
    if (featbf) pk = ((const unsigned int*)bond)[(size_t)b * 64 + cp];
    else {
      float2 f = ((const float2*)bond)[(size_t)b * 64 + cp];
      pk = cvtpk(f.x, f.y);
    }
    if (bondBf) bondBf[(size_t)b * 64 + cp] = pk;
    int d0 = ba[(size_t)(2 * b)     * istr];
    int d1 = ba[(size_t)(2 * b + 1) * istr];
    if (d0 >= 0 && d0 < NA) atomic_pk_add(sums + (size_t)d0 * 64 + cp, pk);
    if (d1 >= 0 && d1 < NA) atomic_pk_add(sums + (size_t)d1 * 64 + cp, pk);
    if (cp == 0) {
      if (d0 >= 0 && d0 < NA) atomicAdd(cnt + d0, 1.0f);
      if (d1 >= 0 && d1 < NA) atomicAdd(cnt + d1, 1.0f);
    }
  }
}

// ---- stage one 16B chunk; prefers pre-converted bf16 sources ----
template<int KIN, int MODE>
__device__ __forceinline__ uint4 stage_chunk(
    int ch, int row0, int rowHi,
    const void* x0, const unsigned int* xBf,
    const void* s1, const float* c1,
    const float* s2, const float* c2,
    const void* gfv, const unsigned int* gBf2,
    const int* idxA, const int* idxS,
    const float* gatherA, const unsigned short* gatherBf,
    int featbf, int istr)
{
  constexpr int CPR = KIN / 8;
  int r = ch / CPR, c8 = ch % CPR;
  int row = row0 + r;
  int seg = c8 * 8;
  if (row >= rowHi) return uint4{0, 0, 0, 0};
  if constexpr (MODE == 0) {
    if (seg < 128) {
      if (xBf) return *(const uint4*)(xBf + (size_t)row * 64 + (seg >> 1));
      return load8bf(x0, (size_t)row * 128 + seg, featbf);
    } else if (seg < 256) {
      return mean8pk(s1, (size_t)row * 64 + ((seg - 128) >> 1), c1[row]);
    } else {
      int g = clampi(idxA[(size_t)row * istr], NG - 1);
      if (gBf2) return *(const uint4*)(gBf2 + (size_t)g * 64 + ((seg - 256) >> 1));
      return load8bf(gfv, (size_t)g * 128 + seg - 256, featbf);
    }
  } else if constexpr (MODE == 1) {
    if (seg < 128) {
      if (xBf) return *(const uint4*)(xBf + (size_t)row * 64 + (seg >> 1));
      return load8bf(x0, (size_t)row * 128 + seg, featbf);
    } else if (seg < 384) {
      int q = (seg < 256) ? 0 : 1;
      int a = clampi(idxA[(size_t)(row * 2 + q) * istr], NA - 1);
      int sc = seg - 128 - q * 128;
      if (gatherBf) return *(const uint4*)(gatherBf + (size_t)a * 128 + sc);
      else          return load8bf(gatherA, (size_t)a * 128 + sc, 0);
    } else {
      int g = clampi(idxS[(size_t)row * istr], NG - 1);
      if (gBf2) return *(const uint4*)(gBf2 + (size_t)g * 64 + ((seg - 384) >> 1));
      return load8bf(gfv, (size_t)g * 128 + seg - 384, featbf);
    }
  } else {
    if (seg < 128) {
      if (xBf) return *(const uint4*)(xBf + (size_t)row * 64 + (seg >> 1));
      return load8bf(x0, (size_t)row * 128 + seg, featbf);
    } else if (seg < 256) {
      return mean8((const float*)s1 + (size_t)row * 128 + seg - 128, c1[row]);
    } else {
      return mean8(s2 + (size_t)row * 128 + seg - 256, c2[row]);
    }
  }
}

// ---- one layer on a 32-row tile; 8 waves, wave w owns col-block w ----
template<int KT, bool FINAL, bool DIRECT>
__device__ __forceinline__ void run_layer32w(
    const char* inbuf, int rowbIn,
    const unsigned short* __restrict__ wpL, const void* __restrict__ biasL, int wbf,
    char* outbuf,
    float* __restrict__ outSec, unsigned short* __restrict__ outBf,
    float* __restrict__ gs, float* __restrict__ gc,
    const int* __restrict__ idxS, int istr, int row0, int rowHi,
    int lane, int wave,
    const unsigned short* __restrict__ gBf, const int* __restrict__ baIdx)
{
  const int colA = lane & 15;
  const int swz = (lane & 7) << 4;
  const int kb = (lane >> 4) << 4;
  const int kbu = (lane >> 4) << 3;
  float bb = ldv(biasL, wave * 16 + colA, wbf);
  f32x4 acc0 = {bb, bb, bb, bb};
  f32x4 acc1 = {bb, bb, bb, bb};

  const unsigned short* pA00; const unsigned short* pA01;
  const unsigned short* pA10; const unsigned short* pA11;
  if constexpr (DIRECT) {
    int r0t = row0 + colA;
    int r1t = r0t + 16;
    pA00 = gBf + (size_t)clampi(baIdx[(size_t)(2 * r0t)     * istr], NA - 1) * 128;
    pA01 = gBf + (size_t)clampi(baIdx[(size_t)(2 * r0t + 1) * istr], NA - 1) * 128;
    pA10 = gBf + (size_t)clampi(baIdx[(size_t)(2 * r1t)     * istr], NA - 1) * 128;
    pA11 = gBf + (size_t)clampi(baIdx[(size_t)(2 * r1t + 1) * istr], NA - 1) * 128;
  }

  #pragma unroll
  for (int kt = 0; kt < KT; ++kt) {
    bf16x8 b = *(const bf16x8*)(wpL + ((size_t)(kt * 8 + wave) << 9) + lane * 8);
    bf16x8 a0, a1;
    bool fromGlobal = DIRECT && kt >= 4 && kt < 12;
    if (fromGlobal) {
      int q  = kt >= 8;
      int kk = (kt - 4 - q * 4) * 32;
      a0 = *(const bf16x8*)((q ? pA01 : pA00) + kk + kbu);
      a1 = *(const bf16x8*)((q ? pA11 : pA10) + kk + kbu);
    } else {
      a0 = *(const bf16x8*)(inbuf + colA * rowbIn + ((kt * 64 + kb) ^ swz));
      a1 = *(const bf16x8*)(inbuf + (16 + colA) * rowbIn + ((kt * 64 + kb) ^ swz));
    }
    acc0 = __builtin_amdgcn_mfma_f32_16x16x32_bf16(a0, b, acc0, 0, 0, 0);
    acc1 = __builtin_amdgcn_mfma_f32_16x16x32_bf16(a1, b, acc1, 0, 0, 0);
  }
  const int col = wave * 16 + colA;
  #pragma unroll
  for (int s = 0; s < 2; s++) {
    f32x4 acc = s ? acc1 : acc0;
    #pragma unroll
    for (int rr = 0; rr < 4; rr++) {
      int row = s * 16 + ((lane >> 4) << 2) + rr;
      float v = acc[rr];
      if (!FINAL) {
        v = softplus_f(v);
        *(unsigned short*)(outbuf + row * 256 + ((col * 2) ^ ((row & 7) << 4))) = f2bf(v);
      } else {
        int grow = row0 + row;
        if (grow < rowHi) {
          outSec[(size_t)grow * 128 + col] = v;
          if (outBf) outBf[(size_t)grow * 128 + col] = f2bf(v);
          if (gs) {
            int g = idxS[(size_t)grow * istr];
            if (g >= 0 && g < NG) {
              atomicAdd(gs + (size_t)g * 128 + col, v);
              if (wave == 0 && colA == 0) atomicAdd(gc + g, 1.0f);
            }
          }
        }
      }
    }
  }
}

// ---- fused 3-layer MFMA MLP over 32-row tiles, 512 threads ----
template<int KIN, int MODE>
__global__ __launch_bounds__(512, 8) void mfma_mlp(
    const void* __restrict__ x0, const unsigned int* __restrict__ xBf,
    const void* __restrict__ s1, const float* __restrict__ c1,
    const float* __restrict__ s2, const float* __restrict__ c2,
    const void* __restrict__ gfv, const unsigned int* __restrict__ gBf2,
    const int* __restrict__ idxA, const int* __restrict__ idxS,
    const float* __restrict__ gatherA, const unsigned short* __restrict__ gatherBf,
    const unsigned short* __restrict__ wp0, const unsigned short* __restrict__ wp1,
    const unsigned short* __restrict__ wp2,
    const void* __restrict__ b0, const void* __restrict__ b1,
    const void* __restrict__ b2,
    float* __restrict__ outSec, unsigned short* __restrict__ outBf,
    float* __restrict__ gs, float* __restrict__ gc,
    int rowHi, const int* __restrict__ fl)
{
  constexpr int ROWB = KIN * 2;
  constexpr int CATB = 32 * ROWB;
  constexpr int CPR  = KIN / 8;
  __shared__ char sm[CATB + 8192];
  char* act0 = sm + CATB;
  char* act1 = sm;
  const int tid = threadIdx.x;
  const int row0 = blockIdx.x * 32;
  const int featbf = fl[0], wbf = fl[1], istr = 1 + fl[2];
  const int lane = tid & 63, wave = tid >> 6;
  const bool direct = (MODE == 1) && (gatherBf != nullptr);

  if (direct) {
    #pragma unroll
    for (int i = 0; i < 2; i++) {
      int ch = tid + i * 512;
      int r = ch >> 5, c5 = ch & 31;
      int c8 = c5 < 16 ? c5 : c5 + 32;
      uint4 h4 = stage_chunk<KIN, MODE>(r * CPR + c8, row0, rowHi, x0, xBf, s1, c1, s2, c2,
                                        gfv, gBf2, idxA, idxS, gatherA, gatherBf, featbf, istr);
      *(uint4*)(sm + r * ROWB + ((c8 * 16) ^ ((r & 7) << 4))) = h4;
    }
  } else {
    for (int ch = tid; ch < 32 * CPR; ch += 512) {
      int r = ch / CPR, c8 = ch % CPR;
      uint4 h4 = stage_chunk<KIN, MODE>(ch, row0, rowHi, x0, xBf, s1, c1, s2, c2,
                                        gfv, gBf2, idxA, idxS, gatherA, gatherBf, featbf, istr);
      *(uint4*)(sm + r * ROWB + ((c8 * 16) ^ ((r & 7) << 4))) = h4;
    }
  }
  __syncthreads();

  if (direct) {
    run_layer32w<KIN / 32, false, true>(sm, ROWB, wp0, b0, wbf, act0,
        nullptr, nullptr, nullptr, nullptr, nullptr, istr, row0, rowHi, lane, wave,
        gatherBf, idxA);
  } else {
    run_layer32w<KIN / 32, false, false>(sm, ROWB, wp0, b0, wbf, act0,
        nullptr, nullptr, nullptr, nullptr, nullptr, istr, row0, rowHi, lane, wave,
        nullptr, nullptr);
  }
  __syncthreads();
  run_layer32w<4, false, false>(act0, 256, wp1, b1, wbf, act1,
      nullptr, nullptr, nullptr, nullptr, nullptr, 1, 0, 0, lane, wave, nullptr, nullptr);
  __syncthreads();
  run_layer32w<4, true, false>(act1, 256, wp2, b2, wbf, nullptr,
      outSec, outBf, gs, gc, idxS, istr, row0, rowHi, lane, wave, nullptr, nullptr);
}

extern "C" void kernel_launch(void* const* d_in, const int* in_sizes, int n_in,
                              void* d_out, int out_size, void* d_ws, size_t ws_size,
                              hipStream_t stream)
{
  const void* atomF = d_in[0];
  const void* bondF = d_in[1];
  const void* globF = d_in[2];
  const int* bondAtom = (const int*)d_in[3];
  const int* atomMol  = (const int*)d_in[4];
  const int* bondMol  = (const int*)d_in[5];
  const void* W[18];
  for (int i = 0; i < 18; i++) W[i] = d_in[6 + i];

  float* outAtom = (float*)d_out;              // f32 (proven R6/R7)
  float* outBond = outAtom + (size_t)NA * 128;
  float* outGlob = outBond + (size_t)NB * 128;

  unsigned int* sums = (unsigned int*)outBond;  // pk edge sums (borrowed)
  float* cnt = outGlob;                         // counts (borrowed)

  // ---- contract validation ----
  const int expect[24] = {
    NA*128, NB*128, NG*128, NB*2, NA, NB,
    384*128, 128, 128*128, 128, 128*128, 128,
    512*128, 128, 128*128, 128, 128*128, 128,
    384*128, 128, 128*128, 128, 128*128, 128 };
  if (n_in != 24) { sentinel<<<1,1,0,stream>>>(outAtom, 8192.0f); return; }
  for (int i = 0; i < 24; i++)
    if (in_sizes[i] != expect[i]) {
      sentinel<<<1,1,0,stream>>>(outAtom, 16384.0f + 256.0f * (float)i);
      return;
    }
  if (out_size != (NA + NB + NG) * 128) {
    sentinel<<<1,1,0,stream>>>(outAtom, 1024.0f); return;
  }

  // ---- ws layout: fl | wp | gs | atomBf | globBf | bondBf | atomFBf ----
  char* ws = (char*)d_ws;
  int* fl = (int*)ws;
  unsigned short* wp = (unsigned short*)(ws + 256);
  const size_t gsOff = 256 + 524288;
  float* gsA = (float*)(ws + gsOff);
  float* gcA = (float*)(ws + gsOff + 5120000);
  float* gsB = (float*)(ws + gsOff + 5160000);
  float* gcB = (float*)(ws + gsOff + 10280000);
  const size_t bfOff = gsOff + 10320000;                   // atomBf: NA*256 B
  unsigned short* atomBf =
      (ws_size >= bfOff + (size_t)NA * 256 + 4096) ? (unsigned short*)(ws + bfOff) : nullptr;
  const size_t gbOff = bfOff + (size_t)NA * 256;           // globBf: NG*256 B
  unsigned int* globBf =
      (atomBf && ws_size >= gbOff + (size_t)NG * 256 + 4096) ? (unsigned int*)(ws + gbOff) : nullptr;
  const size_t bbOff = gbOff + (size_t)NG * 256;           // bondBf: NB*256 B
  unsigned int* bondBf =
      (globBf && ws_size >= bbOff + (size_t)NB * 256 + 4096) ? (unsigned int*)(ws + bbOff) : nullptr;
  const size_t abOff = bbOff + (size_t)NB * 256;           // atomFBf: NA*256 B
  unsigned int* atomFBf =
      (bondBf && ws_size >= abOff + (size_t)NA * 256 + 4096) ? (unsigned int*)(ws + abOff) : nullptr;

  SetupP sp;
  sp.w[0] = W[0];  sp.w[1] = W[2];  sp.w[2] = W[4];
  sp.w[3] = W[6];  sp.w[4] = W[8];  sp.w[5] = W[10];
  sp.w[6] = W[12]; sp.w[7] = W[14]; sp.w[8] = W[16];
  setup_all<<<512, 64, 0, stream>>>(sp, wp, (const unsigned short*)atomF, atomMol, fl);

  hipMemsetAsync(ws + gsOff, 0, 10320000, stream);
  hipMemsetAsync(outBond, 0, (size_t)NA * 256, stream);   // pk edge sums
  hipMemsetAsync(outGlob, 0, (size_t)NA * 4, stream);     // cnt

  if (atomFBf || globBf)
    cvt_feats<<<1024, 256, 0, stream>>>(atomF, globF, atomFBf, globBf, fl);

  // ---- stage 0: edge-mean accumulation (+ free bondBf copy) ----
  edge_sum_pk<<<2048, 256, 0, stream>>>(bondF, bondAtom, sums, cnt, bondBf, fl);

  // ---- stage 1: atoms ----
  mfma_mlp<384, 0><<<(NA + 31) / 32, 512, 0, stream>>>(
      atomF, atomFBf, sums, cnt, nullptr, nullptr, globF, globBf,
      atomMol, atomMol, nullptr, nullptr,
      wp + 0, wp + 49152, wp + 65536, W[1], W[3], W[5],
      outAtom, atomBf, gsA, gcA, NA, fl);

  // ---- stage 2: bonds (direct atomBf fragment gathers in L0) ----
  mfma_mlp<512, 1><<<(NB + 31) / 32, 512, 0, stream>>>(
      bondF, bondBf, nullptr, nullptr, nullptr, nullptr, globF, globBf,
      bondAtom, bondMol, outAtom, atomBf,
      wp + 81920, wp + 147456, wp + 163840, W[7], W[9], W[11],
      outBond, nullptr, gsB, gcB, NB, fl);

  // ---- stage 3: globals ----
  mfma_mlp<384, 2><<<(NG + 31) / 32, 512, 0, stream>>>(
      globF, globBf, gsA, gcA, gsB, gcB, nullptr, nullptr,
      nullptr, nullptr, nullptr, nullptr,
      wp + 180224, wp + 229376, wp + 245760, W[13], W[15], W[17],
      outGlob, nullptr, nullptr, nullptr, NG, fl);
}

// Round 17
// 533.843 us; speedup vs baseline: 1.0672x; 1.0672x over previous
//
#include <hip/hip_runtime.h>
#include <stdint.h>

#define NA 200000
#define NB 200000
#define NG 10000

typedef short bf16x8 __attribute__((ext_vector_type(8)));
typedef float f32x4 __attribute__((ext_vector_type(4)));

__device__ __forceinline__ float bf2f(unsigned short u){
  union { unsigned int i; float f; } v; v.i = ((unsigned int)u) << 16; return v.f;
}
__device__ __forceinline__ unsigned short f2bf(float f){
  union { float f; unsigned int i; } v; v.f = f;
  unsigned int x = v.i;
  unsigned int r = (x + 0x7FFFu + ((x >> 16) & 1u)) >> 16;
  if ((x & 0x7F800000u) == 0x7F800000u) r = x >> 16;
  return (unsigned short)r;
}
__device__ __forceinline__ unsigned int cvtpk(float lo, float hi){
  unsigned int r;
  asm("v_cvt_pk_bf16_f32 %0, %1, %2" : "=v"(r) : "v"(lo), "v"(hi));
  return r;
}
__device__ __forceinline__ void atomic_pk_add(unsigned int* addr, unsigned int pk){
  asm volatile("global_atomic_pk_add_bf16 %0, %1, off" :: "v"(addr), "v"(pk) : "memory");
}
__device__ __forceinline__ unsigned int scale_pk(unsigned int pk, float inv){
  union { unsigned int u; float f; } lo, hi;
  lo.u = pk << 16; hi.u = pk & 0xffff0000u;
  return cvtpk(lo.f * inv, hi.f * inv);
}
__device__ __forceinline__ float softplus_f(float x){
  float t = __builtin_exp2f(-fabsf(x) * 1.44269504089f);
  return fmaxf(x, 0.0f) + 0.69314718056f * __builtin_log2f(1.0f + t);
}
__device__ __forceinline__ float ldv(const void* p, size_t off, int isbf){
  return isbf ? bf2f(((const unsigned short*)p)[off]) : ((const float*)p)[off];
}
__device__ __forceinline__ int clampi(int v, int hi){
  return v < 0 ? 0 : (v > hi ? hi : v);
}
__device__ __forceinline__ uint4 load8bf(const void* p, size_t off, int isbf){
  if (isbf) return *(const uint4*)((const unsigned short*)p + off);
  const float4* f4 = (const float4*)((const float*)p + off);
  float4 a = f4[0], b = f4[1];
  uint4 r;
  r.x = cvtpk(a.x, a.y); r.y = cvtpk(a.z, a.w);
  r.z = cvtpk(b.x, b.y); r.w = cvtpk(b.z, b.w);
  return r;
}
__device__ __forceinline__ uint4 mean8(const float* sp, float cv){
  float inv = cv > 0.f ? 1.f / cv : 0.f;
  const float4* s4 = (const float4*)sp;
  float4 a = s4[0], b = s4[1];
  uint4 r;
  r.x = cvtpk(a.x * inv, a.y * inv); r.y = cvtpk(a.z * inv, a.w * inv);
  r.z = cvtpk(b.x * inv, b.y * inv); r.w = cvtpk(b.z * inv, b.w * inv);
  return r;
}
__device__ __forceinline__ uint4 mean8pk(const void* s, size_t dw, float cv){
  float inv = cv > 0.f ? 1.f / cv : 0.f;
  uint4 p = *(const uint4*)((const unsigned int*)s + dw);
  uint4 r;
  r.x = scale_pk(p.x, inv); r.y = scale_pk(p.y, inv);
  r.z = scale_pk(p.z, inv); r.w = scale_pk(p.w, inv);
  return r;
}
// one MFMA A-fragment (8 consecutive elems) from bf16 or f32 global source
__device__ __forceinline__ bf16x8 gfrag(const void* base, size_t elemOff, bool isbf){
  if (isbf) return *(const bf16x8*)((const unsigned short*)base + elemOff);
  const float4* f = (const float4*)((const float*)base + elemOff);
  float4 a = f[0], b = f[1];
  union { uint4 u; bf16x8 h; } c;
  c.u.x = cvtpk(a.x, a.y); c.u.y = cvtpk(a.z, a.w);
  c.u.z = cvtpk(b.x, b.y); c.u.w = cvtpk(b.z, b.w);
  return c.h;
}

__global__ void sentinel(float* outf, float code){ outf[0] = code; }

// ---- merged setup: probe (block 0) + all weight repacks (512 frag-blocks) ----
struct SetupP { const void* w[9]; };
__global__ __launch_bounds__(64) void setup_all(
    SetupP p, unsigned short* __restrict__ wp,
    const unsigned short* __restrict__ af, const int* __restrict__ amol,
    int* __restrict__ fl)
{
  const int l = threadIdx.x;
  const unsigned short* w0 = (const unsigned short*)p.w[0];
  unsigned short uw = w0[2 * l];
  int ew = (uw >> 7) & 0xFF;
  unsigned long long mw = __ballot(ew >= 0x70 && ew <= 0x8F);
  int wbf = (__popcll(mw) >= 32) ? 1 : 0;
  if (blockIdx.x == 0) {
    unsigned short ua = af[2 * l];
    int ea = (ua >> 7) & 0xFF;
    unsigned long long ma = __ballot(ea >= 0x70 && ea <= 0x8F);
    unsigned long long mi = __ballot(amol[2 * l + 1] == 0);
    if (l == 0) {
      fl[0] = (__popcll(ma) >= 32) ? 1 : 0;
      fl[1] = wbf;
      fl[2] = (__popcll(mi) == 64) ? 1 : 0;
    }
  }
  const int off[10] = {0, 96, 128, 160, 288, 320, 352, 448, 480, 512};
  int b = blockIdx.x;
  int m = 0;
  #pragma unroll
  for (int i = 0; i < 9; i++) if (b >= off[i + 1]) m = i + 1;
  int f = b - off[m];
  const void* w = p.w[m];
  int kt = f >> 3, nb = f & 7;
  alignas(16) unsigned short t[8];
  #pragma unroll
  for (int i = 0; i < 8; i++) {
    size_t o = (size_t)(kt * 32 + ((l >> 4) << 3) + i) * 128 + nb * 16 + (l & 15);
    t[i] = f2bf(ldv(w, o, wbf));
  }
  *(uint4*)(wp + (size_t)b * 512 + l * 8) = *(const uint4*)t;
}

// ---- bond->atom edge sum: packed bf16 atomics ----
__global__ __launch_bounds__(256) void edge_sum_pk(
    const void* __restrict__ bond, const int* __restrict__ ba,
    unsigned int* __restrict__ sums, float* __restrict__ cnt,
    const int* __restrict__ fl)
{
  const int featbf = fl[0];
  const int istr = 1 + fl[2];
  int cp = threadIdx.x & 63;
  int rl = threadIdx.x >> 6;
  for (long b = (long)blockIdx.x * 4 + rl; b < NB; b += (long)gridDim.x * 4) {
    unsigned int pk;
    if (featbf) pk = ((const unsigned int*)bond)[(size_t)b * 64 + cp];
    else {
      float2 f = ((const float2*)bond)[(size_t)b * 64 + cp];
      pk = cvtpk(f.x, f.y);
    }
    int d0 = ba[(size_t)(2 * b)     * istr];
    int d1 = ba[(size_t)(2 * b + 1) * istr];
    if (d0 >= 0 && d0 < NA) atomic_pk_add(sums + (size_t)d0 * 64 + cp, pk);
    if (d1 >= 0 && d1 < NA) atomic_pk_add(sums + (size_t)d1 * 64 + cp, pk);
    if (cp == 0) {
      if (d0 >= 0 && d0 < NA) atomicAdd(cnt + d0, 1.0f);
      if (d1 >= 0 && d1 < NA) atomicAdd(cnt + d1, 1.0f);
    }
  }
}

// ---- stage one 16B chunk of the concatenated input ----
template<int KIN, int MODE>
__device__ __forceinline__ uint4 stage_chunk(
    int ch, int row0, int rowHi,
    const void* x0, const void* s1, const float* c1,
    const float* s2, const float* c2,
    const void* gfv, const int* idxA, const int* idxS,
    int featbf, int istr)
{
  constexpr int CPR = KIN / 8;
  int r = ch / CPR, c8 = ch % CPR;
  int row = row0 + r;
  int seg = c8 * 8;
  if (row >= rowHi) return uint4{0, 0, 0, 0};
  if constexpr (MODE == 0) {
    if (seg < 128)      return load8bf(x0, (size_t)row * 128 + seg, featbf);
    else if (seg < 256) return mean8pk(s1, (size_t)row * 64 + ((seg - 128) >> 1), c1[row]);
    else { int g = clampi(idxA[(size_t)row * istr], NG - 1);
           return load8bf(gfv, (size_t)g * 128 + seg - 256, featbf); }
  } else if constexpr (MODE == 1) {
    // only bond cols (seg<128) and glob cols (seg>=384) are ever staged
    if (seg < 128)      return load8bf(x0, (size_t)row * 128 + seg, featbf);
    else { int g = clampi(idxS[(size_t)row * istr], NG - 1);
           return load8bf(gfv, (size_t)g * 128 + seg - 384, featbf); }
  } else {
    if (seg < 128)      return load8bf(x0, (size_t)row * 128 + seg, featbf);
    else if (seg < 256) return mean8((const float*)s1 + (size_t)row * 128 + seg - 128, c1[row]);
    else                return mean8(s2 + (size_t)row * 128 + seg - 256, c2[row]);
  }
}

// ---- one layer on a 32-row tile; 8 waves, wave w owns col-block w ----
// DIRECT (bond L0): kt 4..11 A-fragments gathered from atom output
// (bf16 atomBf if present, else f32 outAtom); LDS rows are 512B packed.
template<int KT, bool FINAL, bool DIRECT>
__device__ __forceinline__ void run_layer32w(
    const char* inbuf, int rowbIn,
    const unsigned short* __restrict__ wpL, const void* __restrict__ biasL, int wbf,
    char* outbuf,
    float* __restrict__ outSec, unsigned short* __restrict__ outBf,
    float* __restrict__ gs, float* __restrict__ gc,
    const int* __restrict__ idxS, int istr, int row0, int rowHi,
    int lane, int wave,
    const void* __restrict__ gSrc, bool gIsBf, const int* __restrict__ baIdx)
{
  const int colA = lane & 15;
  const int swz = (lane & 7) << 4;
  const int kb = (lane >> 4) << 4;      // byte offset within k-slice (LDS)
  const int kbu = (lane >> 4) << 3;     // element offset (global fragments)
  float bb = ldv(biasL, wave * 16 + colA, wbf);
  f32x4 acc0 = {bb, bb, bb, bb};
  f32x4 acc1 = {bb, bb, bb, bb};

  size_t rA00 = 0, rA01 = 0, rA10 = 0, rA11 = 0;
  if constexpr (DIRECT) {
    int r0t = row0 + colA;
    int r1t = r0t + 16;
    rA00 = (size_t)clampi(baIdx[(size_t)(2 * r0t)     * istr], NA - 1) * 128;
    rA01 = (size_t)clampi(baIdx[(size_t)(2 * r0t + 1) * istr], NA - 1) * 128;
    rA10 = (size_t)clampi(baIdx[(size_t)(2 * r1t)     * istr], NA - 1) * 128;
    rA11 = (size_t)clampi(baIdx[(size_t)(2 * r1t + 1) * istr], NA - 1) * 128;
  }

  #pragma unroll
  for (int kt = 0; kt < KT; ++kt) {
    bf16x8 b = *(const bf16x8*)(wpL + ((size_t)(kt * 8 + wave) << 9) + lane * 8);
    bf16x8 a0, a1;
    bool fromGlobal = DIRECT && kt >= 4 && kt < 12;
    if (fromGlobal) {
      int q  = kt >= 8;
      size_t kk = (size_t)(kt - 4 - q * 4) * 32 + kbu;
      a0 = gfrag(gSrc, (q ? rA01 : rA00) + kk, gIsBf);
      a1 = gfrag(gSrc, (q ? rA11 : rA10) + kk, gIsBf);
    } else {
      // DIRECT LDS map: kt<4 -> off kt*64; kt>=12 -> off (kt-8)*64
      int ktoff = (!DIRECT || kt < 4) ? kt * 64 : (kt - 8) * 64;
      a0 = *(const bf16x8*)(inbuf + colA * rowbIn + ((ktoff + kb) ^ swz));
      a1 = *(const bf16x8*)(inbuf + (16 + colA) * rowbIn + ((ktoff + kb) ^ swz));
    }
    acc0 = __builtin_amdgcn_mfma_f32_16x16x32_bf16(a0, b, acc0, 0, 0, 0);
    acc1 = __builtin_amdgcn_mfma_f32_16x16x32_bf16(a1, b, acc1, 0, 0, 0);
  }
  const int col = wave * 16 + colA;
  #pragma unroll
  for (int s = 0; s < 2; s++) {
    f32x4 acc = s ? acc1 : acc0;
    #pragma unroll
    for (int rr = 0; rr < 4; rr++) {
      int row = s * 16 + ((lane >> 4) << 2) + rr;
      float v = acc[rr];
      if (!FINAL) {
        v = softplus_f(v);
        *(unsigned short*)(outbuf + row * 256 + ((col * 2) ^ ((row & 7) << 4))) = f2bf(v);
      } else {
        int grow = row0 + row;
        if (grow < rowHi) {
          outSec[(size_t)grow * 128 + col] = v;
          if (outBf) outBf[(size_t)grow * 128 + col] = f2bf(v);
          if (gs) {
            int g = idxS[(size_t)grow * istr];
            if (g >= 0 && g < NG) {
              atomicAdd(gs + (size_t)g * 128 + col, v);
              if (wave == 0 && colA == 0) atomicAdd(gc + g, 1.0f);
            }
          }
        }
      }
    }
  }
}

// ---- fused 3-layer MFMA MLP over 32-row tiles, 512 threads ----
// MODE 0: atom  cat=[atom | mean(pk s1,c1) | glob[amol]]  ROWB=768, LDS 32KB
// MODE 1: bond  packed cat=[bond | glob] 512B rows,       LDS 24KB (4 blk/CU)
// MODE 2: glob  cat=[glob | meanA | meanB]                ROWB=768
template<int KIN, int MODE>
__global__ __launch_bounds__(512, 8) void mfma_mlp(
    const void* __restrict__ x0,
    const void* __restrict__ s1, const float* __restrict__ c1,
    const float* __restrict__ s2, const float* __restrict__ c2,
    const void* __restrict__ gfv,
    const int* __restrict__ idxA, const int* __restrict__ idxS,
    const float* __restrict__ gatherA, const unsigned short* __restrict__ gatherBf,
    const unsigned short* __restrict__ wp0, const unsigned short* __restrict__ wp1,
    const unsigned short* __restrict__ wp2,
    const void* __restrict__ b0, const void* __restrict__ b1,
    const void* __restrict__ b2,
    float* __restrict__ outSec, unsigned short* __restrict__ outBf,
    float* __restrict__ gs, float* __restrict__ gc,
    int rowHi, const int* __restrict__ fl)
{
  constexpr int ROWB = (MODE == 1) ? 512 : KIN * 2;
  constexpr int CATB = 32 * ROWB;
  constexpr int CPR  = KIN / 8;
  __shared__ char sm[CATB + 8192];
  char* act0 = sm + CATB;
  char* act1 = sm;          // aliases cat (dead after L0)
  const int tid = threadIdx.x;
  const int row0 = blockIdx.x * 32;
  const int featbf = fl[0], wbf = fl[1], istr = 1 + fl[2];
  const int lane = tid & 63, wave = tid >> 6;

  // ---- stage input tile ----
  if constexpr (MODE == 1) {
    #pragma unroll
    for (int i = 0; i < 2; i++) {                // 1024 chunks / 512 threads
      int ch = tid + i * 512;
      int r = ch >> 5, c5 = ch & 31;
      int c8 = c5 < 16 ? c5 : c5 + 32;           // bond cols + glob cols only
      uint4 h4 = stage_chunk<KIN, MODE>(r * CPR + c8, row0, rowHi, x0, s1, c1, s2, c2,
                                        gfv, idxA, idxS, featbf, istr);
      *(uint4*)(sm + r * 512 + ((c5 * 16) ^ ((r & 7) << 4))) = h4;
    }
  } else {
    for (int ch = tid; ch < 32 * CPR; ch += 512) {
      int r = ch / CPR, c8 = ch % CPR;
      uint4 h4 = stage_chunk<KIN, MODE>(ch, row0, rowHi, x0, s1, c1, s2, c2,
                                        gfv, idxA, idxS, featbf, istr);
      *(uint4*)(sm + r * ROWB + ((c8 * 16) ^ ((r & 7) << 4))) = h4;
    }
  }
  __syncthreads();

  if constexpr (MODE == 1) {
    const void* gSrc = gatherBf ? (const void*)gatherBf : (const void*)gatherA;
    run_layer32w<KIN / 32, false, true>(sm, ROWB, wp0, b0, wbf, act0,
        nullptr, nullptr, nullptr, nullptr, nullptr, istr, row0, rowHi, lane, wave,
        gSrc, gatherBf != nullptr, idxA);
  } else {
    run_layer32w<KIN / 32, false, false>(sm, ROWB, wp0, b0, wbf, act0,
        nullptr, nullptr, nullptr, nullptr, nullptr, istr, row0, rowHi, lane, wave,
        nullptr, true, nullptr);
  }
  __syncthreads();
  run_layer32w<4, false, false>(act0, 256, wp1, b1, wbf, act1,
      nullptr, nullptr, nullptr, nullptr, nullptr, 1, 0, 0, lane, wave,
      nullptr, true, nullptr);
  __syncthreads();
  run_layer32w<4, true, false>(act1, 256, wp2, b2, wbf, nullptr,
      outSec, outBf, gs, gc, idxS, istr, row0, rowHi, lane, wave,
      nullptr, true, nullptr);
}

extern "C" void kernel_launch(void* const* d_in, const int* in_sizes, int n_in,
                              void* d_out, int out_size, void* d_ws, size_t ws_size,
                              hipStream_t stream)
{
  const void* atomF = d_in[0];
  const void* bondF = d_in[1];
  const void* globF = d_in[2];
  const int* bondAtom = (const int*)d_in[3];
  const int* atomMol  = (const int*)d_in[4];
  const int* bondMol  = (const int*)d_in[5];
  const void* W[18];
  for (int i = 0; i < 18; i++) W[i] = d_in[6 + i];

  float* outAtom = (float*)d_out;              // f32 (proven R6/R7)
  float* outBond = outAtom + (size_t)NA * 128;
  float* outGlob = outBond + (size_t)NB * 128;

  unsigned int* sums = (unsigned int*)outBond;  // pk edge sums (borrowed)
  float* cnt = outGlob;                         // counts (borrowed)

  // ---- contract validation ----
  const int expect[24] = {
    NA*128, NB*128, NG*128, NB*2, NA, NB,
    384*128, 128, 128*128, 128, 128*128, 128,
    512*128, 128, 128*128, 128, 128*128, 128,
    384*128, 128, 128*128, 128, 128*128, 128 };
  if (n_in != 24) { sentinel<<<1,1,0,stream>>>(outAtom, 8192.0f); return; }
  for (int i = 0; i < 24; i++)
    if (in_sizes[i] != expect[i]) {
      sentinel<<<1,1,0,stream>>>(outAtom, 16384.0f + 256.0f * (float)i);
      return;
    }
  if (out_size != (NA + NB + NG) * 128) {
    sentinel<<<1,1,0,stream>>>(outAtom, 1024.0f); return;
  }

  // ---- ws layout: fl | wp 512KB | gs f32 10.32MB | [opt] atomBf 51.2MB ----
  char* ws = (char*)d_ws;
  int* fl = (int*)ws;
  unsigned short* wp = (unsigned short*)(ws + 256);
  const size_t gsOff = 256 + 524288;
  float* gsA = (float*)(ws + gsOff);
  float* gcA = (float*)(ws + gsOff + 5120000);
  float* gsB = (float*)(ws + gsOff + 5160000);
  float* gcB = (float*)(ws + gsOff + 10280000);
  const size_t bfOff = gsOff + 10320000;
  unsigned short* atomBf =
      (ws_size >= bfOff + (size_t)NA * 256 + 4096) ? (unsigned short*)(ws + bfOff) : nullptr;

  SetupP sp;
  sp.w[0] = W[0];  sp.w[1] = W[2];  sp.w[2] = W[4];
  sp.w[3] = W[6];  sp.w[4] = W[8];  sp.w[5] = W[10];
  sp.w[6] = W[12]; sp.w[7] = W[14]; sp.w[8] = W[16];
  setup_all<<<512, 64, 0, stream>>>(sp, wp, (const unsigned short*)atomF, atomMol, fl);

  hipMemsetAsync(ws + gsOff, 0, 10320000, stream);
  hipMemsetAsync(outBond, 0, (size_t)NA * 256, stream);   // pk edge sums
  hipMemsetAsync(outGlob, 0, (size_t)NA * 4, stream);     // cnt

  // ---- stage 0: edge-mean accumulation ----
  edge_sum_pk<<<2048, 256, 0, stream>>>(bondF, bondAtom, sums, cnt, fl);

  // ---- stage 1: atoms ----
  mfma_mlp<384, 0><<<(NA + 31) / 32, 512, 0, stream>>>(
      atomF, sums, cnt, nullptr, nullptr, globF, atomMol, atomMol, nullptr, nullptr,
      wp + 0, wp + 49152, wp + 65536, W[1], W[3], W[5],
      outAtom, atomBf, gsA, gcA, NA, fl);

  // ---- stage 2: bonds (direct gathers in L0; 512B packed LDS rows) ----
  mfma_mlp<512, 1><<<(NB + 31) / 32, 512, 0, stream>>>(
      bondF, nullptr, nullptr, nullptr, nullptr, globF, bondAtom, bondMol,
      outAtom, atomBf,
      wp + 81920, wp + 147456, wp + 163840, W[7], W[9], W[11],
      outBond, nullptr, gsB, gcB, NB, fl);

  // ---- stage 3: globals ----
  mfma_mlp<384, 2><<<(NG + 31) / 32, 512, 0, stream>>>(
      globF, gsA, gcA, gsB, gcB, nullptr, nullptr, nullptr, nullptr, nullptr,
      wp + 180224, wp + 229376, wp + 245760, W[13], W[15], W[17],
      outGlob, nullptr, nullptr, nullptr, NG, fl);
}